// Round 6
// baseline (142.142 us; speedup 1.0000x reference)
//
#include <hip/hip_runtime.h>
#include <hip/hip_bf16.h>

namespace {
constexpr int NODES = 100000;
constexpr int EMBD  = 128;
constexpr int BATCH = 1024;
constexpr int STRIP = 320;          // node cols per block: 1280 B/row = 10 lines
constexpr int NI    = STRIP / 16;   // 20 MFMA col-tiles
constexpr int TAILC = NODES % STRIP;        // 160
constexpr int TAIL_NI = TAILC / 16;         // 10
constexpr int NBLK  = NODES / STRIP + 1;    // 313 (312 full + 1 tail)
constexpr int NPASS = 8;            // 1024 rows / (4 waves * 32 rows)
}

typedef __attribute__((ext_vector_type(8))) short bf16x8_t;
typedef __attribute__((ext_vector_type(4))) float f32x4_t;

__device__ __forceinline__ short f2bf(float f) {
    __hip_bfloat16 h = __float2bfloat16(f);
    short s; __builtin_memcpy(&s, &h, 2); return s;
}

// combined[b][k] = emb[subj[b]][k] * rels[rel[b]][k], bf16 (A matrix, 256 KB)
__global__ void combine_kernel(const int* __restrict__ subj,
                               const int* __restrict__ rel,
                               const float* __restrict__ emb,
                               const float* __restrict__ rels,
                               short* __restrict__ out) {
    const int b = blockIdx.x;
    const int t = threadIdx.x;
    const float v = emb[(size_t)subj[b] * EMBD + t] * rels[rel[b] * EMBD + t];
    out[b * EMBD + t] = f2bf(v);
}

// C[m][n] = sum_k A[m][k]*B[n][k]
// Block = 320-col node strip x all 1024 batch rows, 4 waves, 80 KB dynamic LDS.
// B strip: fp32 read ONCE (coalesced), cvt->bf16, XOR-swizzled into LDS
// (byte ^= (row&7)<<4) -> conflict-free ds_read_b128 fragments; one barrier,
// then the 8-pass row sweep is barrier-free (LDS read-only).
// Swapped-operand MFMA: D col(lane&15)=batch row, D row(fq*4+reg)=node
//   -> f32x4 stores along N; per row each block writes 1280 B contiguous.
// Tail block (312): cols 99840..99999 -> store only first TAIL_NI tiles.
__global__ __launch_bounds__(256, 2) void distmult_kernel(
        const short* __restrict__ A,
        const float* __restrict__ B,
        float* __restrict__ C) {
    extern __shared__ short Bs[];          // STRIP*EMBD bf16 = 80 KB
    const int n0  = blockIdx.x * STRIP;
    const int tid = (int)threadIdx.x;

    // ---- stage B strip: 40960 bf16 elems, 160/thread (20 chunks of 8)
#pragma unroll
    for (int c = 0; c < 20; ++c) {
        const int e = (c * 256 + tid) * 8;       // flat elem index
        const int r = e >> 7;                    // node row in strip (0..319)
        const int k = e & 127;                   // k col (multiple of 8)
        int row = n0 + r; if (row >= NODES) row = NODES - 1;   // tail clamp
        const float* p = B + (size_t)row * EMBD + k;
        f32x4_t lo = *reinterpret_cast<const f32x4_t*>(p);
        f32x4_t hi = *reinterpret_cast<const f32x4_t*>(p + 4);
        bf16x8_t v;
#pragma unroll
        for (int j = 0; j < 4; ++j) { v[j] = f2bf(lo[j]); v[4 + j] = f2bf(hi[j]); }
        const int byteaddr = r * 256 + ((k * 2) ^ ((r & 7) << 4));
        *reinterpret_cast<bf16x8_t*>(reinterpret_cast<char*>(Bs) + byteaddr) = v;
    }
    __syncthreads();

    const int w  = tid >> 6;
    const int l  = tid & 63;
    const int fr = l & 15;
    const int fq = l >> 4;
    const int swz = (fr & 7) << 4;               // lane's XOR key
    const bool full = (n0 + STRIP) <= NODES;     // block-uniform

    const char* BsBase = reinterpret_cast<const char*>(Bs) + fr * 256;

#pragma unroll
    for (int p = 0; p < NPASS; ++p) {
        const int m0 = p * 128 + w * 32;
        bf16x8_t a[2][4];
#pragma unroll
        for (int mi = 0; mi < 2; ++mi) {
            const short* q = A + (m0 + mi * 16 + fr) * EMBD + fq * 8;
#pragma unroll
            for (int kk = 0; kk < 4; ++kk)
                a[mi][kk] = *reinterpret_cast<const bf16x8_t*>(q + kk * 32);
        }

        f32x4_t acc[2][NI] = {};
#pragma unroll
        for (int kk = 0; kk < 4; ++kk) {
#pragma unroll
            for (int h = 0; h < NI / 5; ++h) {   // groups of 5 cap live B regs
                bf16x8_t bfr[5];
#pragma unroll
                for (int j = 0; j < 5; ++j) {
                    const int ni = h * 5 + j;
                    const int byteoff = ni * 4096 + ((kk * 64 + fq * 16) ^ swz);
                    bfr[j] = *reinterpret_cast<const bf16x8_t*>(BsBase + byteoff);
                }
#pragma unroll
                for (int mi = 0; mi < 2; ++mi)
#pragma unroll
                    for (int j = 0; j < 5; ++j)
                        acc[mi][h * 5 + j] = __builtin_amdgcn_mfma_f32_16x16x32_bf16(
                            bfr[j], a[mi][kk], acc[mi][h * 5 + j], 0, 0, 0);
            }
        }

        if (full) {
#pragma unroll
            for (int mi = 0; mi < 2; ++mi) {
                const size_t rowoff = (size_t)(m0 + mi * 16 + fr) * NODES;
#pragma unroll
                for (int ni = 0; ni < NI; ++ni)
                    *reinterpret_cast<f32x4_t*>(C + rowoff + n0 + ni * 16 + fq * 4) =
                        acc[mi][ni];
            }
        } else {
#pragma unroll
            for (int mi = 0; mi < 2; ++mi) {
                const size_t rowoff = (size_t)(m0 + mi * 16 + fr) * NODES;
#pragma unroll
                for (int ni = 0; ni < TAIL_NI; ++ni)
                    *reinterpret_cast<f32x4_t*>(C + rowoff + n0 + ni * 16 + fq * 4) =
                        acc[mi][ni];
            }
        }
    }
}

extern "C" void kernel_launch(void* const* d_in, const int* in_sizes, int n_in,
                              void* d_out, int out_size, void* d_ws, size_t ws_size,
                              hipStream_t stream) {
    const int*   subj = (const int*)d_in[0];
    const int*   rel  = (const int*)d_in[1];
    const float* emb  = (const float*)d_in[2];
    const float* rels = (const float*)d_in[3];
    float* out = (float*)d_out;
    short* combined = (short*)d_ws;   // 256 KB

    combine_kernel<<<BATCH, EMBD, 0, stream>>>(subj, rel, emb, rels, combined);
    distmult_kernel<<<NBLK, 256, STRIP * EMBD * sizeof(short), stream>>>(
        combined, emb, out);
}

// Round 7
// 114.010 us; speedup vs baseline: 1.2467x; 1.2467x over previous
//
#include <hip/hip_runtime.h>
#include <hip/hip_bf16.h>

namespace {
constexpr int NODES = 100000;
constexpr int EMBD  = 128;
constexpr int BATCH = 1024;
constexpr int STRIP = 160;    // 160 cols * 4 B = 640 B/row; 100000/160 = 625 blocks
constexpr int NI    = 10;     // 16-col MFMA tiles per strip
constexpr int NPASS = 8;      // 1024 rows / (4 waves * 32 rows)
}

typedef __attribute__((ext_vector_type(8))) short bf16x8_t;
typedef __attribute__((ext_vector_type(4))) float f32x4_t;

__device__ __forceinline__ short f2bf(float f) {
    __hip_bfloat16 h = __float2bfloat16(f);
    short s; __builtin_memcpy(&s, &h, 2); return s;
}

// combined[b][k] = emb[subj[b]][k] * rels[rel[b]][k], bf16 (A matrix, 256 KB)
__global__ void combine_kernel(const int* __restrict__ subj,
                               const int* __restrict__ rel,
                               const float* __restrict__ emb,
                               const float* __restrict__ rels,
                               short* __restrict__ out) {
    const int b = blockIdx.x;
    const int t = threadIdx.x;
    const float v = emb[(size_t)subj[b] * EMBD + t] * rels[rel[b] * EMBD + t];
    out[b * EMBD + t] = f2bf(v);
}

// C[m][n] = sum_k A[m][k]*B[n][k]
// Block = 160-col node strip x all 1024 batch rows, 4 waves, 40 KB LDS.
// B strip: fp32 read ONCE, cvt->bf16, XOR-swizzled LDS -> conflict-free
// ds_read_b128; one barrier, then barrier-free 8-pass row sweep.
// DEFERRED-STORE PIPELINE: pass p issues {A loads for p} then {stores of
// pass p-1's acc} then MFMA. A-load wait leaves stores in flight (counted
// vmcnt), so store drain overlaps next-pass compute instead of serializing.
// Swapped-operand MFMA: D col(lane&15)=batch row, D row(fq*4+reg)=node.
__global__ __launch_bounds__(256, 3) void distmult_kernel(
        const short* __restrict__ A,
        const float* __restrict__ B,
        float* __restrict__ C) {
    __shared__ short Bs[STRIP * EMBD];     // 40 KB
    const int n0  = blockIdx.x * STRIP;
    const int tid = (int)threadIdx.x;

    // ---- stage B strip: 20480 bf16 elems, 80/thread (10 chunks of 8)
#pragma unroll
    for (int c = 0; c < 10; ++c) {
        const int e = (c * 256 + tid) * 8;
        const int r = e >> 7;
        const int k = e & 127;
        const float* p = B + (size_t)(n0 + r) * EMBD + k;
        f32x4_t lo = *reinterpret_cast<const f32x4_t*>(p);
        f32x4_t hi = *reinterpret_cast<const f32x4_t*>(p + 4);
        bf16x8_t v;
#pragma unroll
        for (int j = 0; j < 4; ++j) { v[j] = f2bf(lo[j]); v[4 + j] = f2bf(hi[j]); }
        const int byteaddr = r * 256 + ((k * 2) ^ ((r & 7) << 4));
        *reinterpret_cast<bf16x8_t*>(reinterpret_cast<char*>(Bs) + byteaddr) = v;
    }
    __syncthreads();

    const int w  = tid >> 6;
    const int l  = tid & 63;
    const int fr = l & 15;
    const int fq = l >> 4;
    const int swz = (fr & 7) << 4;
    const char* BsBase = reinterpret_cast<const char*>(Bs) + fr * 256;

    f32x4_t acc[2][NI];   // carried across passes; stored one pass late

#pragma unroll
    for (int p = 0; p < NPASS; ++p) {
        const int m0 = p * 128 + w * 32;

        // 1) issue this pass's A loads (L2-hot) FIRST
        bf16x8_t a[2][4];
#pragma unroll
        for (int mi = 0; mi < 2; ++mi) {
            const short* q = A + (m0 + mi * 16 + fr) * EMBD + fq * 8;
#pragma unroll
            for (int kk = 0; kk < 4; ++kk)
                a[mi][kk] = *reinterpret_cast<const bf16x8_t*>(q + kk * 32);
        }

        // 2) issue previous pass's stores (stay in flight during MFMA)
        if (p > 0) {
            const int m0p = (p - 1) * 128 + w * 32;
#pragma unroll
            for (int mi = 0; mi < 2; ++mi) {
                const size_t rowoff = (size_t)(m0p + mi * 16 + fr) * NODES;
#pragma unroll
                for (int ni = 0; ni < NI; ++ni)
                    *reinterpret_cast<f32x4_t*>(C + rowoff + n0 + ni * 16 + fq * 4) =
                        acc[mi][ni];
            }
        }

        // 3) compute this pass (acc regs reusable once store data is read)
#pragma unroll
        for (int mi = 0; mi < 2; ++mi)
#pragma unroll
            for (int ni = 0; ni < NI; ++ni)
                acc[mi][ni] = f32x4_t{0.f, 0.f, 0.f, 0.f};

#pragma unroll
        for (int kk = 0; kk < 4; ++kk) {
#pragma unroll
            for (int h = 0; h < 2; ++h) {
                bf16x8_t bfr[5];
#pragma unroll
                for (int j = 0; j < 5; ++j) {
                    const int ni = h * 5 + j;
                    const int byteoff = ni * 4096 + ((kk * 64 + fq * 16) ^ swz);
                    bfr[j] = *reinterpret_cast<const bf16x8_t*>(BsBase + byteoff);
                }
#pragma unroll
                for (int mi = 0; mi < 2; ++mi)
#pragma unroll
                    for (int j = 0; j < 5; ++j)
                        acc[mi][h * 5 + j] = __builtin_amdgcn_mfma_f32_16x16x32_bf16(
                            bfr[j], a[mi][kk], acc[mi][h * 5 + j], 0, 0, 0);
            }
        }
    }

    // epilogue: store final pass
    {
        const int m0p = (NPASS - 1) * 128 + w * 32;
#pragma unroll
        for (int mi = 0; mi < 2; ++mi) {
            const size_t rowoff = (size_t)(m0p + mi * 16 + fr) * NODES;
#pragma unroll
            for (int ni = 0; ni < NI; ++ni)
                *reinterpret_cast<f32x4_t*>(C + rowoff + n0 + ni * 16 + fq * 4) =
                    acc[mi][ni];
        }
    }
}

extern "C" void kernel_launch(void* const* d_in, const int* in_sizes, int n_in,
                              void* d_out, int out_size, void* d_ws, size_t ws_size,
                              hipStream_t stream) {
    const int*   subj = (const int*)d_in[0];
    const int*   rel  = (const int*)d_in[1];
    const float* emb  = (const float*)d_in[2];
    const float* rels = (const float*)d_in[3];
    float* out = (float*)d_out;
    short* combined = (short*)d_ws;   // 256 KB

    combine_kernel<<<BATCH, EMBD, 0, stream>>>(subj, rel, emb, rels, combined);
    distmult_kernel<<<NODES / STRIP, 256, 0, stream>>>(combined, emb, out);
}